// Round 18
// baseline (73.939 us; speedup 1.0000x reference)
//
#include <hip/hip_runtime.h>
#include <hip/hip_bf16.h>

// Problem: B=4, N=1024, C=1024, H=16, D=64.  epoch=25 -> band window w=8.
// 4 dispatches:
//   convert_xw: x,Wqkv fp32 -> bf16 (R11 body)
//   gemm1_qkv8: m201-style 8-phase 256x256xBK64 pipeline, counted vmcnt,
//               raw s_barrier, 2dbuf x 4 half-regions, race map verified.
//   attn_band_mfma, gemm2_proj: R10 verbatim.

typedef __bf16 bf16x8_t __attribute__((ext_vector_type(8)));
typedef unsigned short u16x8_t __attribute__((ext_vector_type(8)));
typedef float f32x4_t __attribute__((ext_vector_type(4)));

__device__ __forceinline__ void load_lds16(const void* g, void* l) {
    __builtin_amdgcn_global_load_lds(
        (__attribute__((address_space(1))) void*)(g),
        (__attribute__((address_space(3))) void*)(l),
        16, 0, 0);
}

__device__ __forceinline__ u16x8_t cvt8(float4 u, float4 v) {
    union { u16x8_t p; __hip_bfloat16 h[8]; } w;
    w.h[0] = __float2bfloat16(u.x); w.h[1] = __float2bfloat16(u.y);
    w.h[2] = __float2bfloat16(u.z); w.h[3] = __float2bfloat16(u.w);
    w.h[4] = __float2bfloat16(v.x); w.h[5] = __float2bfloat16(v.y);
    w.h[6] = __float2bfloat16(v.z); w.h[7] = __float2bfloat16(v.w);
    return w.p;
}

// ---------------- fp32 -> bf16 conversion (x, Wqkv) --------------------------
__global__ __launch_bounds__(256) void convert_xw(
    const float* __restrict__ x, const float* __restrict__ wqkv,
    __hip_bfloat16* __restrict__ xb, __hip_bfloat16* __restrict__ wqkvb)
{
    const size_t t = (size_t)blockIdx.x * 256 + threadIdx.x;
    size_t i = t * 8;
    const float* src;
    __hip_bfloat16* dst;
    if (i < 4194304) {
        src = x; dst = xb;
    } else {
        src = wqkv; dst = wqkvb; i -= 4194304;
    }
    float4 v0 = *reinterpret_cast<const float4*>(src + i);
    float4 v1 = *reinterpret_cast<const float4*>(src + i + 4);
    *reinterpret_cast<u16x8_t*>(dst + i) = cvt8(v0, v1);
}

// ---------------- GEMM1: qkv = xb @ wqkvb^T, 8-phase pipeline ---------------
// 256x256 tile, BK=64, grid 16x12=192 blocks, 8 waves (2M x 4N, 128x64/wave).
// LDS: 2 dbuf x {A-mh0,A-mh1,B-nh0,B-nh1} x 16KB = 128KB.
// Phase (d,mh,nh): 12 ds_read_b128 + 1 half-tile stage + 16 MFMA.
// Stage map (iter i, kt0=2i): ph1 A1->d1[kt0+1], ph2 B1->d1[kt0+1],
//   ph3 A0->d0[kt0+2], ph4 B0->d0[kt0+2], ph5 A1->d0[kt0+2],
//   ph6 B1->d0[kt0+2], ph7 A0->d1[kt0+3], ph8 B0->d1[kt0+3].
// Each stage issues one barrier after its region's last reader (verified);
// vmcnt(8)@ph1,ph5 + vmcnt(6)@ph2,ph6 guarantee landing before first read.
__global__ __launch_bounds__(512, 2) void gemm1_qkv8(
    const __hip_bfloat16* __restrict__ A,   // xb [4096,1024]
    const __hip_bfloat16* __restrict__ B,   // wqkvb [3072,1024]
    __hip_bfloat16* __restrict__ C)         // [4096,3072]
{
    __shared__ __align__(16) char smem[131072];
    const int tid = threadIdx.x;
    const int orig = blockIdx.y * 12 + blockIdx.x;
    const int wgid = (orig & 7) * 24 + (orig >> 3);   // bijective: 192 = 8*24
    const int m0 = (wgid / 12) * 256, n0 = (wgid % 12) * 256;

    const int wave = tid >> 6, lane = tid & 63;
    const int wr = wave >> 2, wc = wave & 3;
    const int lr = lane & 15, kg = lane >> 4;

    // stage sources: region chunk q in {tid, tid+512}; rr=q>>3, slot=q&7,
    // source col-chunk = slot ^ (rr&7).  (tid+512 has same swizzle value.)
    const int rr = tid >> 3;                         // 0..63
    const int cch = (tid & 7) ^ (rr & 7);
    const __hip_bfloat16* ApSrc0 = A + (size_t)(m0 + rr) * 1024 + cch * 8;
    const __hip_bfloat16* ApSrc1 = A + (size_t)(m0 + 128 + rr) * 1024 + cch * 8;
    const __hip_bfloat16* BpSrc0 = B + (size_t)(n0 + (rr >> 5) * 64 + (rr & 31)) * 1024 + cch * 8;
    const __hip_bfloat16* BpSrc1 = B + (size_t)(n0 + 128 + (rr >> 5) * 64 + (rr & 31)) * 1024 + cch * 8;

#define STAGE_A(D, MH, KT) if ((KT) < 16) {                                     \
    const size_t o_ = (size_t)(MH) * 65536 + (size_t)(KT) * 64;                 \
    load_lds16(ApSrc0 + o_, smem + (D) * 65536 + (MH) * 16384 + tid * 16);      \
    load_lds16(ApSrc1 + o_, smem + (D) * 65536 + (MH) * 16384 + (tid + 512) * 16); }
#define STAGE_B(D, NH, KT) if ((KT) < 16) {                                     \
    const size_t o_ = (size_t)(NH) * 32768 + (size_t)(KT) * 64;                 \
    load_lds16(BpSrc0 + o_, smem + (D) * 65536 + 32768 + (NH) * 16384 + tid * 16); \
    load_lds16(BpSrc1 + o_, smem + (D) * 65536 + 32768 + (NH) * 16384 + (tid + 512) * 16); }

    f32x4_t acc[8][4] = {};
    const int aBase = (wr * 64 + lr) * 128;          // + mi2*2048
    const int bBase = (wc * 32 + lr) * 128;          // + ni2*2048
    const int ch0 = ((kg) ^ (lr & 7)) * 16;
    const int ch1 = ((4 + kg) ^ (lr & 7)) * 16;

#define VMW(N) asm volatile("s_waitcnt vmcnt(" #N ")" ::: "memory")

#define PH(D, MH, NH, STMT) {                                                   \
    __builtin_amdgcn_s_barrier();                                               \
    bf16x8_t aF[4][2], bF[2][2];                                                \
    _Pragma("unroll") for (int mi2 = 0; mi2 < 4; ++mi2) {                       \
        const int rb_ = (D) * 65536 + (MH) * 16384 + aBase + mi2 * 2048;        \
        aF[mi2][0] = *(const bf16x8_t*)(smem + rb_ + ch0);                      \
        aF[mi2][1] = *(const bf16x8_t*)(smem + rb_ + ch1); }                    \
    _Pragma("unroll") for (int ni2 = 0; ni2 < 2; ++ni2) {                       \
        const int rb_ = (D) * 65536 + 32768 + (NH) * 16384 + bBase + ni2 * 2048;\
        bF[ni2][0] = *(const bf16x8_t*)(smem + rb_ + ch0);                      \
        bF[ni2][1] = *(const bf16x8_t*)(smem + rb_ + ch1); }                    \
    STMT;                                                                       \
    __builtin_amdgcn_s_setprio(1);                                              \
    _Pragma("unroll") for (int ks = 0; ks < 2; ++ks)                            \
    _Pragma("unroll") for (int mi2 = 0; mi2 < 4; ++mi2)                         \
    _Pragma("unroll") for (int ni2 = 0; ni2 < 2; ++ni2)                         \
        acc[(MH) * 4 + mi2][(NH) * 2 + ni2] =                                   \
            __builtin_amdgcn_mfma_f32_16x16x32_bf16(                            \
                aF[mi2][ks], bF[ni2][ks], acc[(MH) * 4 + mi2][(NH) * 2 + ni2],  \
                0, 0, 0);                                                       \
    __builtin_amdgcn_s_setprio(0); }

    // prologue = issue history of virtual iter -1 phases 3..8
    STAGE_A(0, 0, 0); STAGE_B(0, 0, 0);
    STAGE_A(0, 1, 0); STAGE_B(0, 1, 0);
    STAGE_A(1, 0, 1); STAGE_B(1, 0, 1);

    for (int it = 0; it < 8; ++it) {
        const int k0 = 2 * it;
        VMW(8); PH(0, 0, 0, STAGE_A(1, 1, k0 + 1));
        VMW(6); PH(0, 0, 1, STAGE_B(1, 1, k0 + 1));
                PH(0, 1, 0, STAGE_A(0, 0, k0 + 2));
                PH(0, 1, 1, STAGE_B(0, 0, k0 + 2));
        VMW(8); PH(1, 0, 0, STAGE_A(0, 1, k0 + 2));
        VMW(6); PH(1, 0, 1, STAGE_B(0, 1, k0 + 2));
                PH(1, 1, 0, STAGE_A(1, 0, k0 + 3));
                PH(1, 1, 1, STAGE_B(1, 0, k0 + 3));
    }
#undef PH
#undef VMW
#undef STAGE_A
#undef STAGE_B

    // epilogue: 2 passes of 128 rows via [128][264] bf16 image, 16B stores
    __syncthreads();
    __hip_bfloat16* cl = (__hip_bfloat16*)smem;
#pragma unroll
    for (int p = 0; p < 2; ++p) {
        if (p) __syncthreads();
        if (wr == p) {
#pragma unroll
            for (int mi = 0; mi < 8; ++mi)
#pragma unroll
                for (int ni = 0; ni < 4; ++ni)
#pragma unroll
                    for (int r = 0; r < 4; ++r)
                        cl[((mi >> 2) * 64 + (mi & 3) * 16 + kg * 4 + r) * 264 +
                           wc * 64 + (ni >> 1) * 32 + (ni & 1) * 16 + lr] =
                            __float2bfloat16(acc[mi][ni][r]);
        }
        __syncthreads();
#pragma unroll
        for (int c = 0; c < 8; ++c) {
            const int ch = tid + c * 512;        // 4096 = 128 rows x 32 chunks
            const int row = ch >> 5, cc = ch & 31;
            f32x4_t v = *(const f32x4_t*)(smem + row * 528 + cc * 16);
            *(f32x4_t*)((char*)C + ((size_t)(m0 + p * 128 + row) * 3072 + n0) * 2 +
                        cc * 16) = v;
        }
    }
}

// ---------------- GEMM2: out = ctx @ WprojT + bias (fp32 out) ----------------
__global__ __launch_bounds__(512, 2) void gemm2_proj(
    const __hip_bfloat16* __restrict__ A,   // ctx [4096,1024] bf16
    const float* __restrict__ B,            // Wproj [1024,1024] fp32
    float* __restrict__ C,                  // [4096,1024]
    const float* __restrict__ bias)
{
    __shared__ __align__(16) char smem[65536];
    const int tid = threadIdx.x;
    const int orig = blockIdx.y * 8 + blockIdx.x;
    const int wgid = (orig & 7) * 32 + (orig >> 3);
    const int m0 = (wgid >> 3) * 128, n0 = (wgid & 7) * 128;

    const int wave = tid >> 6, lane = tid & 63;
    const int wr = wave >> 2, wc = wave & 3;
    const int lr = lane & 15, kg = lane >> 4;
    const int K = 1024, Nn = 1024;

    const int q = tid;
    const int row = q >> 2, cw = ((q & 3) ^ ((row >> 1) & 3)) * 8;
    const __hip_bfloat16* Ap = A + (size_t)(m0 + row) * K + cw;
    const float*          Bp = B + (size_t)(n0 + row) * K + cw;

    float4 av = {}, bv0 = {}, bv1 = {};

#define LOADR2(t) { const int ko_ = (t) * 32;                                  \
    av  = *(const float4*)(Ap + ko_);                                          \
    bv0 = *(const float4*)(Bp + ko_); bv1 = *(const float4*)(Bp + ko_ + 4); }
#define WRITE2(t) { char* d_ = smem + ((t) & 3) * 16384;                       \
    *(float4*)(d_ + q * 16) = av;                                              \
    *(u16x8_t*)(d_ + 8192 + q * 16) = cvt8(bv0, bv1); }

    f32x4_t acc[4][2] = {};
    const int rsw = ((kg ^ ((lr >> 1) & 3)) * 16);
    const int arow = wr * 64 + lr;
    const int brow = wc * 32 + lr;

    LOADR2(0); WRITE2(0);
    LOADR2(1); WRITE2(1);
    LOADR2(2);
    __syncthreads();

    for (int t = 0; t < 32; ++t) {
        const int sb_ = (t & 3) * 16384;
        bf16x8_t a_[4], b_[2];
#pragma unroll
        for (int mi = 0; mi < 4; ++mi)
            a_[mi] = *(const bf16x8_t*)(smem + sb_ + (arow + mi * 16) * 64 + rsw);
#pragma unroll
        for (int ni = 0; ni < 2; ++ni)
            b_[ni] = *(const bf16x8_t*)(smem + sb_ + 8192 + (brow + ni * 16) * 64 + rsw);
        if (t < 30) WRITE2(t + 2);
        if (t < 29) LOADR2(t + 3);
        __builtin_amdgcn_s_setprio(1);
#pragma unroll
        for (int mi = 0; mi < 4; ++mi)
#pragma unroll
            for (int ni = 0; ni < 2; ++ni)
                acc[mi][ni] = __builtin_amdgcn_mfma_f32_16x16x32_bf16(
                    a_[mi], b_[ni], acc[mi][ni], 0, 0, 0);
        __builtin_amdgcn_s_setprio(0);
        __syncthreads();
    }
#undef LOADR2
#undef WRITE2

    float* cf = (float*)smem;
#pragma unroll
    for (int p = 0; p < 2; ++p) {
        if (p) __syncthreads();
        if (wr == p) {
#pragma unroll
            for (int mi = 0; mi < 4; ++mi)
#pragma unroll
                for (int ni = 0; ni < 2; ++ni) {
                    const int scol = wc * 32 + ni * 16 + lr;
#pragma unroll
                    for (int r = 0; r < 4; ++r)
                        cf[(mi * 16 + kg * 4 + r) * 132 + scol] = acc[mi][ni][r];
                }
        }
        __syncthreads();
#pragma unroll
        for (int cc = 0; cc < 4; ++cc) {
            const int chunk = tid + cc * 512;
            const int srow = chunk >> 5;
            const int sc = (chunk & 31) * 4;
            f32x4_t v = *(const f32x4_t*)(smem + srow * 528 + sc * 4);
            const f32x4_t bv = *(const f32x4_t*)(bias + n0 + sc);
            v += bv;
            *(f32x4_t*)(C + (size_t)(m0 + p * 64 + srow) * Nn + n0 + sc) = v;
        }
    }
}

// ---------------- banded MFMA attention, block-shared K/V --------------------
__global__ __launch_bounds__(256) void attn_band_mfma(
    const __hip_bfloat16* __restrict__ qkv,
    __hip_bfloat16* __restrict__ ctx,
    const int* __restrict__ epoch_ptr)
{
    __shared__ __align__(16) __hip_bfloat16 K_lds[128 * 64];
    __shared__ __align__(16) __hip_bfloat16 V_lds[64 * 136];
    __shared__ __hip_bfloat16 P_lds[4][16 * 40];

    const int tid = threadIdx.x;
    const int wave = tid >> 6, lane = tid & 63;
    const int lr = lane & 15, kg = lane >> 4;

    const int bid = blockIdx.x;
    const int tg = bid & 15;
    const int bh = bid >> 4;
    const int h = bh & 15, b = bh >> 4;
    const int base = tg * 64;
    const int i0 = base + wave * 16;

    const int e = *epoch_ptr;
    int w;
    if      (e < 20) w = 6;
    else if (e < 30) w = 8;
    else if (e < 40) w = 10;
    else if (e < 50) w = 12;
    else             w = 1023;

    const size_t rowb = (size_t)b * 1024;
    const int hq = h * 192;

#pragma unroll
    for (int it = 0; it < 4; ++it) {
        const int q = tid + it * 256;
        const int row = q >> 3, s = q & 7;
        const int c = s ^ (row & 7);
        int gk = base - 32 + row;
        gk = gk < 0 ? 0 : (gk > 1023 ? 1023 : gk);
        load_lds16(qkv + (rowb + gk) * 3072 + hq + 64 + c * 8,
                   (char*)K_lds + q * 16);
    }
    {
        const int pr = tid & 63, dg = tid >> 6;
        int gk0 = base - 32 + 2 * pr, gk1 = gk0 + 1;
        gk0 = gk0 < 0 ? 0 : (gk0 > 1023 ? 1023 : gk0);
        gk1 = gk1 < 0 ? 0 : (gk1 > 1023 ? 1023 : gk1);
        const __hip_bfloat16* v0 = qkv + (rowb + gk0) * 3072 + hq + 128 + dg * 16;
        const __hip_bfloat16* v1 = qkv + (rowb + gk1) * 3072 + hq + 128 + dg * 16;
        u16x8_t a0 = *(const u16x8_t*)v0, b0 = *(const u16x8_t*)(v0 + 8);
        u16x8_t a1 = *(const u16x8_t*)v1, b1 = *(const u16x8_t*)(v1 + 8);
#pragma unroll
        for (int c2 = 0; c2 < 8; ++c2) {
            *(unsigned int*)&V_lds[(dg * 16 + c2) * 136 + 2 * pr] =
                (unsigned int)a0[c2] | ((unsigned int)a1[c2] << 16);
            *(unsigned int*)&V_lds[(dg * 16 + 8 + c2) * 136 + 2 * pr] =
                (unsigned int)b0[c2] | ((unsigned int)b1[c2] << 16);
        }
    }

    bf16x8_t aq[2];
#pragma unroll
    for (int ks = 0; ks < 2; ++ks)
        aq[ks] = *(const bf16x8_t*)(qkv + (rowb + i0 + lr) * 3072 + hq + ks * 32 + kg * 8);

    __syncthreads();

    float m[4] = {-1e30f, -1e30f, -1e30f, -1e30f};
    float l[4] = {0.f, 0.f, 0.f, 0.f};
    f32x4_t o[4] = {};

    int jlo = i0 - w;      if (jlo < 0) jlo = 0;
    int jhi = i0 + 15 + w; if (jhi > 1023) jhi = 1023;
    const int t0 = (base >> 5) - 1;

    for (int p = (jlo >> 5); p <= (jhi >> 5); ++p) {
        const int kb = p * 32;
        const int tl = p - t0;

        f32x4_t s2[2] = {};
#pragma unroll
        for (int t = 0; t < 2; ++t)
#pragma unroll
            for (int ks = 0; ks < 2; ++ks) {
                const int lkr = tl * 32 + t * 16 + lr;
                bf16x8_t bk = *(const bf16x8_t*)(
                    (char*)K_lds + lkr * 128 + (((ks * 4 + kg) ^ (lr & 7)) * 16));
                s2[t] = __builtin_amdgcn_mfma_f32_16x16x32_bf16(aq[ks], bk, s2[t], 0, 0, 0);
            }

        float sv[2][4];
#pragma unroll
        for (int t = 0; t < 2; ++t)
#pragma unroll
            for (int r = 0; r < 4; ++r) {
                const int qi = i0 + kg * 4 + r;
                const int j  = kb + t * 16 + lr;
                int d = qi - j; if (d < 0) d = -d;
                sv[t][r] = (d <= w) ? s2[t][r] * 0.125f : -1e30f;
            }

        float tm[4];
#pragma unroll
        for (int r = 0; r < 4; ++r) tm[r] = fmaxf(sv[0][r], sv[1][r]);
#pragma unroll
        for (int msk = 1; msk < 16; msk <<= 1)
#pragma unroll
            for (int r = 0; r < 4; ++r) tm[r] = fmaxf(tm[r], __shfl_xor(tm[r], msk));

        float sc[4], ps[4], pvv[2][4];
#pragma unroll
        for (int r = 0; r < 4; ++r) {
            const float mn = fmaxf(m[r], tm[r]);
            sc[r] = __expf(m[r] - mn);
            pvv[0][r] = __expf(sv[0][r] - mn);
            pvv[1][r] = __expf(sv[1][r] - mn);
            ps[r] = pvv[0][r] + pvv[1][r];
            m[r] = mn;
        }
#pragma unroll
        for (int msk = 1; msk < 16; msk <<= 1)
#pragma unroll
            for (int r = 0; r < 4; ++r) ps[r] += __shfl_xor(ps[r], msk);
#pragma unroll
        for (int r = 0; r < 4; ++r) l[r] = l[r] * sc[r] + ps[r];
#pragma unroll
        for (int ni = 0; ni < 4; ++ni)
#pragma unroll
            for (int r = 0; r < 4; ++r) o[ni][r] *= sc[r];

#pragma unroll
        for (int t = 0; t < 2; ++t)
#pragma unroll
            for (int r = 0; r < 4; ++r)
                P_lds[wave][(kg * 4 + r) * 40 + t * 16 + lr] =
                    __float2bfloat16(pvv[t][r]);

        bf16x8_t ap = *(const bf16x8_t*)&P_lds[wave][lr * 40 + kg * 8];
#pragma unroll
        for (int ni = 0; ni < 4; ++ni) {
            bf16x8_t bv = *(const bf16x8_t*)&V_lds[(ni * 16 + lr) * 136 + tl * 32 + kg * 8];
            o[ni] = __builtin_amdgcn_mfma_f32_16x16x32_bf16(ap, bv, o[ni], 0, 0, 0);
        }
    }

#pragma unroll
    for (int ni = 0; ni < 4; ++ni)
#pragma unroll
        for (int r = 0; r < 4; ++r)
            ctx[(rowb + i0 + kg * 4 + r) * 1024 + h * 64 + ni * 16 + lr] =
                __float2bfloat16(o[ni][r] / l[r]);
}

// ---------------- launch -----------------------------------------------------
extern "C" void kernel_launch(void* const* d_in, const int* in_sizes, int n_in,
                              void* d_out, int out_size, void* d_ws, size_t ws_size,
                              hipStream_t stream)
{
    const float* x     = (const float*)d_in[0];
    const float* Wqkv  = (const float*)d_in[1];
    const float* Wproj = (const float*)d_in[2];
    const float* bproj = (const float*)d_in[3];
    const int*   epoch = (const int*)d_in[4];

    char* ws = (char*)d_ws;
    __hip_bfloat16* xb    = (__hip_bfloat16*)(ws);
    __hip_bfloat16* wqkvb = (__hip_bfloat16*)(ws + 8388608);
    __hip_bfloat16* qkvb  = (__hip_bfloat16*)(ws + 16777216);
    __hip_bfloat16* ctxb  = (__hip_bfloat16*)(ws + 16777216 + 25165824);

    convert_xw<<<3584, 256, 0, stream>>>(x, Wqkv, xb, wqkvb);

    gemm1_qkv8<<<dim3(12, 16), 512, 0, stream>>>(xb, wqkvb, qkvb);

    attn_band_mfma<<<1024, 256, 0, stream>>>(qkvb, ctxb, epoch);

    gemm2_proj<<<dim3(8, 32), 512, 0, stream>>>(
        ctxb, Wproj, (float*)d_out, bproj);
}